// Round 1
// baseline (393.244 us; speedup 1.0000x reference)
//
#include <hip/hip_runtime.h>
#include <hip/hip_bf16.h>
#include <math.h>

// Multi-Query Attention, B=1, S=2048, D=2048, 16 heads x 128, causal.
// Strategy: fp32 -> fp16 casts, all matmuls on v_mfma_f32_16x16x32_f16
// (fp32 accumulate), flash-style attention, fp16 staging buffers in d_ws.

#define S_LEN 2048
#define DMODEL 2048
#define EQKV 2304
#define HDIM 128
#define NHEADS 16

typedef _Float16 f16;
typedef __attribute__((ext_vector_type(8))) _Float16 f16x8;
typedef __attribute__((ext_vector_type(4))) _Float16 f16x4;
typedef __attribute__((ext_vector_type(4))) float f32x4;

#define MFMA16(a, b, c) __builtin_amdgcn_mfma_f32_16x16x32_f16((a), (b), (c), 0, 0, 0)

__device__ __forceinline__ void load_lds16(const void* g, void* l) {
  // global -> LDS direct, 16B per lane. LDS dest is wave-uniform base + lane*16.
  __builtin_amdgcn_global_load_lds((const __attribute__((address_space(1))) void*)g,
                                   (__attribute__((address_space(3))) void*)l, 16, 0, 0);
}

// ---------------- fp32 -> fp16 conversion (exact-grid, 4 elems/thread) ----
__global__ void f32_to_f16_kernel(const float* __restrict__ in, f16* __restrict__ out, int n4) {
  int i = blockIdx.x * blockDim.x + threadIdx.x;
  if (i < n4) {
    float4 v = reinterpret_cast<const float4*>(in)[i];
    f16x4 o = {(f16)v.x, (f16)v.y, (f16)v.z, (f16)v.w};
    reinterpret_cast<f16x4*>(out)[i] = o;
  }
}

// ---------------- GEMM: C[M][N] = A[M][K] * B[N][K]^T + bias --------------
// BM=64 BN=128 BK=64, 256 thr (2x2 waves of 32x64). XOR-swizzled LDS
// (chunk ^= row&7) with pre-swizzled global source (both-sides rule).
// QKV mode: n-block 17 (cols 2176..2303) is V -> written transposed to VT.
template <typename OutT, bool QKV>
__global__ __launch_bounds__(256) void gemm_bt(
    const f16* __restrict__ A, const f16* __restrict__ Bm,
    const float* __restrict__ bias, OutT* __restrict__ C,
    f16* __restrict__ VT, int M, int N, int K) {
  __shared__ __align__(16) char smem[24576];  // A: 8KB, B: 16KB
  const int tid = threadIdx.x;
  const int w = tid >> 6;
  const int l = tid & 63;
  const int bm = blockIdx.x, bn = blockIdx.y;
  const int wm = w >> 1, wn = w & 1;
  const int lg = l >> 4;   // 0..3
  const int lm = l & 15;   // 0..15
  const int l7 = l & 7;

  f32x4 acc[2][4] = {};

  // Swizzled LDS byte offsets for fragment reads (row stride 128B = 8 chunks).
  int aoff[2][2], boff[4][2];
#pragma unroll
  for (int mf = 0; mf < 2; ++mf) {
    int row = wm * 32 + mf * 16 + lm;
#pragma unroll
    for (int kk = 0; kk < 2; ++kk)
      aoff[mf][kk] = row * 128 + ((kk * 4 + lg) ^ l7) * 16;
  }
#pragma unroll
  for (int nf = 0; nf < 4; ++nf) {
    int row = wn * 64 + nf * 16 + lm;
#pragma unroll
    for (int kk = 0; kk < 2; ++kk)
      boff[nf][kk] = 8192 + row * 128 + ((kk * 4 + lg) ^ l7) * 16;
  }

  const int nkt = K >> 6;
  for (int kt = 0; kt < nkt; ++kt) {
    const int k0 = kt << 6;
    // ---- stage A (2 insts) + B (4 insts), source pre-swizzled ----
#pragma unroll
    for (int i = 0; i < 2; ++i) {
      int slot = i * 256 + w * 64 + l;
      int row = slot >> 3;
      int cg = (slot & 7) ^ (row & 7);
      const f16* g = A + (size_t)(bm * 64 + row) * K + k0 + cg * 8;
      load_lds16(g, smem + (i * 256 + w * 64) * 16);
    }
#pragma unroll
    for (int i = 0; i < 4; ++i) {
      int slot = i * 256 + w * 64 + l;
      int row = slot >> 3;
      int cg = (slot & 7) ^ (row & 7);
      const f16* g = Bm + (size_t)(bn * 128 + row) * K + k0 + cg * 8;
      load_lds16(g, smem + 8192 + (i * 256 + w * 64) * 16);
    }
    __syncthreads();  // drains vmcnt for global_load_lds
    // ---- compute: 2 k-steps of 16 MFMAs ----
#pragma unroll
    for (int kk = 0; kk < 2; ++kk) {
      f16x8 af[2], bf[4];
#pragma unroll
      for (int mf = 0; mf < 2; ++mf)
        af[mf] = *reinterpret_cast<const f16x8*>(smem + aoff[mf][kk]);
#pragma unroll
      for (int nf = 0; nf < 4; ++nf)
        bf[nf] = *reinterpret_cast<const f16x8*>(smem + boff[nf][kk]);
#pragma unroll
      for (int mf = 0; mf < 2; ++mf)
#pragma unroll
        for (int nf = 0; nf < 4; ++nf)
          acc[mf][nf] = MFMA16(af[mf], bf[nf], acc[mf][nf]);
    }
    __syncthreads();  // protect LDS before next stage
  }

  // ---- epilogue: D layout row=(l>>4)*4+j, col=l&15 ----
#pragma unroll
  for (int mf = 0; mf < 2; ++mf) {
#pragma unroll
    for (int nf = 0; nf < 4; ++nf) {
      int col = bn * 128 + wn * 64 + nf * 16 + lm;
      float bv = bias[col];
#pragma unroll
      for (int j = 0; j < 4; ++j) {
        int row = bm * 64 + wm * 32 + mf * 16 + lg * 4 + j;
        float v = acc[mf][nf][j] + bv;
        if (QKV && col >= DMODEL + HDIM) {
          VT[(size_t)(col - DMODEL - HDIM) * S_LEN + row] = (f16)v;  // V transposed
        } else {
          C[(size_t)row * N + col] = (OutT)v;
        }
      }
    }
  }
}

// ---------------- Flash MQA attention ------------------------------------
// Block = 2 waves x 32 q-rows (2 m-frags of 16). KBLK=64. Q hoisted to regs.
// K and V^T fragments read directly from global (L2-resident, 512KB each).
// Online softmax in fp32 (exp2-based). P bounced via padded LDS [32][72].
__global__ __launch_bounds__(128) void flash_mqa(
    const f16* __restrict__ qkv, const f16* __restrict__ vt, f16* __restrict__ ctx) {
  __shared__ __align__(16) f16 Plds[2][32][72];
  const int tid = threadIdx.x;
  const int wv = tid >> 6;
  const int l = tid & 63;
  const int lg = l >> 4, lm = l & 15;
  const int head = blockIdx.y;
  const int qt = blockIdx.x;
  const int wq0 = qt * 64 + wv * 32;
  const float alpha = 0.08838834764831845f * 1.4426950408889634f;  // scale*log2e

  // Q fragments: A[m=lm][k=ks*32+lg*8+i], kept in registers for all KV tiles.
  f16x8 qf[2][4];
#pragma unroll
  for (int mf = 0; mf < 2; ++mf)
#pragma unroll
    for (int ks = 0; ks < 4; ++ks)
      qf[mf][ks] = *reinterpret_cast<const f16x8*>(
          qkv + (size_t)(wq0 + mf * 16 + lm) * EQKV + head * HDIM + ks * 32 + lg * 8);

  f32x4 o[2][8] = {};
  float m_row[2][4], l_row[2][4];
#pragma unroll
  for (int mf = 0; mf < 2; ++mf)
#pragma unroll
    for (int j = 0; j < 4; ++j) {
      m_row[mf][j] = -__builtin_inff();
      l_row[mf][j] = 0.f;
    }

  const int nt = qt + 1;  // causal: tiles 0..qt
  for (int t = 0; t < nt; ++t) {
    const int k0 = t * 64;
    // ---- scores: S[32][64] = Q * K^T ----
    f32x4 sc[2][4] = {};
#pragma unroll
    for (int ks = 0; ks < 4; ++ks) {
#pragma unroll
      for (int nf = 0; nf < 4; ++nf) {
        f16x8 kf = *reinterpret_cast<const f16x8*>(
            qkv + (size_t)(k0 + nf * 16 + lm) * EQKV + DMODEL + ks * 32 + lg * 8);
        sc[0][nf] = MFMA16(qf[0][ks], kf, sc[0][nf]);
        sc[1][nf] = MFMA16(qf[1][ks], kf, sc[1][nf]);
      }
    }
    // ---- causal mask (diagonal tile only) ----
    if (t == nt - 1) {
#pragma unroll
      for (int mf = 0; mf < 2; ++mf)
#pragma unroll
        for (int nf = 0; nf < 4; ++nf)
#pragma unroll
          for (int j = 0; j < 4; ++j) {
            int row = wq0 + mf * 16 + lg * 4 + j;
            int col = k0 + nf * 16 + lm;
            if (col > row) sc[mf][nf][j] = -__builtin_inff();
          }
    }
    // ---- online softmax per m-frag ----
#pragma unroll
    for (int mf = 0; mf < 2; ++mf) {
      float tm[4], rj[4], rs[4];
#pragma unroll
      for (int j = 0; j < 4; ++j)
        tm[j] = fmaxf(fmaxf(sc[mf][0][j], sc[mf][1][j]), fmaxf(sc[mf][2][j], sc[mf][3][j]));
#pragma unroll
      for (int j = 0; j < 4; ++j) {
#pragma unroll
        for (int d = 1; d < 16; d <<= 1) tm[j] = fmaxf(tm[j], __shfl_xor(tm[j], d));
      }
#pragma unroll
      for (int j = 0; j < 4; ++j) {
        float mn = fmaxf(m_row[mf][j], tm[j] * alpha);
        rj[j] = exp2f(m_row[mf][j] - mn);  // exp2(-inf)=0 on first tile
        m_row[mf][j] = mn;
        l_row[mf][j] *= rj[j];
        rs[j] = 0.f;
      }
#pragma unroll
      for (int nf = 0; nf < 4; ++nf)
#pragma unroll
        for (int j = 0; j < 4; ++j) {
          float p = exp2f(sc[mf][nf][j] * alpha - m_row[mf][j]);
          rs[j] += p;
          Plds[wv][mf * 16 + lg * 4 + j][nf * 16 + lm] = (f16)p;
        }
#pragma unroll
      for (int j = 0; j < 4; ++j) {
#pragma unroll
        for (int d = 1; d < 16; d <<= 1) rs[j] += __shfl_xor(rs[j], d);
        l_row[mf][j] += rs[j];
      }
#pragma unroll
      for (int df = 0; df < 8; ++df)
#pragma unroll
        for (int j = 0; j < 4; ++j) o[mf][df][j] *= rj[j];
    }
    // P writes must land before A-frag reads (cross-lane through LDS)
    asm volatile("s_waitcnt lgkmcnt(0)" ::: "memory");
    __builtin_amdgcn_sched_barrier(0);
    // ---- PV: O += P[32][64] * V[64][128] (V^T rows are contiguous) ----
#pragma unroll
    for (int kk = 0; kk < 2; ++kk) {
      f16x8 pa[2];
#pragma unroll
      for (int mf = 0; mf < 2; ++mf)
        pa[mf] = *reinterpret_cast<const f16x8*>(&Plds[wv][mf * 16 + lm][kk * 32 + lg * 8]);
#pragma unroll
      for (int df = 0; df < 8; ++df) {
        f16x8 vf = *reinterpret_cast<const f16x8*>(
            vt + (size_t)(df * 16 + lm) * S_LEN + k0 + kk * 32 + lg * 8);
        o[0][df] = MFMA16(pa[0], vf, o[0][df]);
        o[1][df] = MFMA16(pa[1], vf, o[1][df]);
      }
    }
  }
  // ---- epilogue: ctx = O / l ----
#pragma unroll
  for (int mf = 0; mf < 2; ++mf)
#pragma unroll
    for (int j = 0; j < 4; ++j) {
      float inv = 1.0f / l_row[mf][j];
      int row = wq0 + mf * 16 + lg * 4 + j;
#pragma unroll
      for (int df = 0; df < 8; ++df)
        ctx[(size_t)row * DMODEL + head * HDIM + df * 16 + lm] =
            (f16)(o[mf][df][j] * inv);
    }
}

// ---------------- host launcher -------------------------------------------
extern "C" void kernel_launch(void* const* d_in, const int* in_sizes, int n_in,
                              void* d_out, int out_size, void* d_ws, size_t ws_size,
                              hipStream_t stream) {
  const float* x = (const float*)d_in[0];
  const float* Wqkv_w = (const float*)d_in[1];
  const float* Wqkv_b = (const float*)d_in[2];
  const float* out_w = (const float*)d_in[3];
  const float* out_b = (const float*)d_in[4];

  char* p = (char*)d_ws;
  f16* xh = (f16*)p;    p += (size_t)S_LEN * DMODEL * 2;   // 8 MB
  f16* wqh = (f16*)p;   p += (size_t)EQKV * DMODEL * 2;    // 9 MB
  f16* owh = (f16*)p;   p += (size_t)DMODEL * DMODEL * 2;  // 8 MB
  f16* qkvh = (f16*)p;  p += (size_t)S_LEN * EQKV * 2;     // 9 MB
  f16* vth = (f16*)p;   p += (size_t)HDIM * S_LEN * 2;     // 0.5 MB
  f16* ctxh = (f16*)p;  p += (size_t)S_LEN * DMODEL * 2;   // 8 MB

  // fp32 -> fp16 (exact grids; all counts divisible by 1024)
  f32_to_f16_kernel<<<(S_LEN * DMODEL / 4) / 256, 256, 0, stream>>>(x, xh, S_LEN * DMODEL / 4);
  f32_to_f16_kernel<<<(EQKV * DMODEL / 4) / 256, 256, 0, stream>>>(Wqkv_w, wqh, EQKV * DMODEL / 4);
  f32_to_f16_kernel<<<(DMODEL * DMODEL / 4) / 256, 256, 0, stream>>>(out_w, owh, DMODEL * DMODEL / 4);

  // QKV projection (writes q,k into qkvh; v transposed into vth)
  gemm_bt<f16, true><<<dim3(S_LEN / 64, EQKV / 128), 256, 0, stream>>>(
      xh, wqh, Wqkv_b, qkvh, vth, S_LEN, EQKV, DMODEL);

  // causal MQA flash attention
  flash_mqa<<<dim3(S_LEN / 64, NHEADS), 128, 0, stream>>>(qkvh, vth, ctxh);

  // output projection (fp32 out + bias)
  gemm_bt<float, false><<<dim3(S_LEN / 64, DMODEL / 128), 256, 0, stream>>>(
      ctxh, owh, out_b, (float*)d_out, nullptr, S_LEN, DMODEL, DMODEL);
}

// Round 2
// 312.059 us; speedup vs baseline: 1.2602x; 1.2602x over previous
//
#include <hip/hip_runtime.h>
#include <hip/hip_bf16.h>
#include <math.h>

// Multi-Query Attention, B=1, S=2048, D=2048, 16 heads x 128, causal.
// fp32 -> fp16 casts, all matmuls on v_mfma_f32_16x16x32_f16 (fp32 accum).
// R2: split-KV flash attention (flash-decode style) to fix 6% occupancy.

#define S_LEN 2048
#define DMODEL 2048
#define EQKV 2304
#define HDIM 128
#define NHEADS 16

typedef _Float16 f16;
typedef __attribute__((ext_vector_type(8))) _Float16 f16x8;
typedef __attribute__((ext_vector_type(4))) _Float16 f16x4;
typedef __attribute__((ext_vector_type(4))) float f32x4;

#define MFMA16(a, b, c) __builtin_amdgcn_mfma_f32_16x16x32_f16((a), (b), (c), 0, 0, 0)

__device__ __forceinline__ void load_lds16(const void* g, void* l) {
  __builtin_amdgcn_global_load_lds((const __attribute__((address_space(1))) void*)g,
                                   (__attribute__((address_space(3))) void*)l, 16, 0, 0);
}

// ---------------- fp32 -> fp16 conversion ---------------------------------
__global__ void f32_to_f16_kernel(const float* __restrict__ in, f16* __restrict__ out, int n4) {
  int i = blockIdx.x * blockDim.x + threadIdx.x;
  if (i < n4) {
    float4 v = reinterpret_cast<const float4*>(in)[i];
    f16x4 o = {(f16)v.x, (f16)v.y, (f16)v.z, (f16)v.w};
    reinterpret_cast<f16x4*>(out)[i] = o;
  }
}

// ---------------- GEMM: C[M][N] = A[M][K] * B[N][K]^T + bias --------------
// BM=64 BN=128 BK=64, 256 thr (2x2 waves of 32x64). XOR-swizzled LDS.
// QKV mode: cols 2176..2303 are V -> written transposed to VT.
template <typename OutT, bool QKV>
__global__ __launch_bounds__(256) void gemm_bt(
    const f16* __restrict__ A, const f16* __restrict__ Bm,
    const float* __restrict__ bias, OutT* __restrict__ C,
    f16* __restrict__ VT, int M, int N, int K) {
  __shared__ __align__(16) char smem[24576];  // A: 8KB, B: 16KB
  const int tid = threadIdx.x;
  const int w = tid >> 6;
  const int l = tid & 63;
  const int bm = blockIdx.x, bn = blockIdx.y;
  const int wm = w >> 1, wn = w & 1;
  const int lg = l >> 4;
  const int lm = l & 15;
  const int l7 = l & 7;

  f32x4 acc[2][4] = {};

  int aoff[2][2], boff[4][2];
#pragma unroll
  for (int mf = 0; mf < 2; ++mf) {
    int row = wm * 32 + mf * 16 + lm;
#pragma unroll
    for (int kk = 0; kk < 2; ++kk)
      aoff[mf][kk] = row * 128 + ((kk * 4 + lg) ^ l7) * 16;
  }
#pragma unroll
  for (int nf = 0; nf < 4; ++nf) {
    int row = wn * 64 + nf * 16 + lm;
#pragma unroll
    for (int kk = 0; kk < 2; ++kk)
      boff[nf][kk] = 8192 + row * 128 + ((kk * 4 + lg) ^ l7) * 16;
  }

  const int nkt = K >> 6;
  for (int kt = 0; kt < nkt; ++kt) {
    const int k0 = kt << 6;
#pragma unroll
    for (int i = 0; i < 2; ++i) {
      int slot = i * 256 + w * 64 + l;
      int row = slot >> 3;
      int cg = (slot & 7) ^ (row & 7);
      const f16* g = A + (size_t)(bm * 64 + row) * K + k0 + cg * 8;
      load_lds16(g, smem + (i * 256 + w * 64) * 16);
    }
#pragma unroll
    for (int i = 0; i < 4; ++i) {
      int slot = i * 256 + w * 64 + l;
      int row = slot >> 3;
      int cg = (slot & 7) ^ (row & 7);
      const f16* g = Bm + (size_t)(bn * 128 + row) * K + k0 + cg * 8;
      load_lds16(g, smem + 8192 + (i * 256 + w * 64) * 16);
    }
    __syncthreads();
#pragma unroll
    for (int kk = 0; kk < 2; ++kk) {
      f16x8 af[2], bf[4];
#pragma unroll
      for (int mf = 0; mf < 2; ++mf)
        af[mf] = *reinterpret_cast<const f16x8*>(smem + aoff[mf][kk]);
#pragma unroll
      for (int nf = 0; nf < 4; ++nf)
        bf[nf] = *reinterpret_cast<const f16x8*>(smem + boff[nf][kk]);
#pragma unroll
      for (int mf = 0; mf < 2; ++mf)
#pragma unroll
        for (int nf = 0; nf < 4; ++nf)
          acc[mf][nf] = MFMA16(af[mf], bf[nf], acc[mf][nf]);
    }
    __syncthreads();
  }

#pragma unroll
  for (int mf = 0; mf < 2; ++mf) {
#pragma unroll
    for (int nf = 0; nf < 4; ++nf) {
      int col = bn * 128 + wn * 64 + nf * 16 + lm;
      float bv = bias[col];
#pragma unroll
      for (int j = 0; j < 4; ++j) {
        int row = bm * 64 + wm * 32 + mf * 16 + lg * 4 + j;
        float v = acc[mf][nf][j] + bv;
        if (QKV && col >= DMODEL + HDIM) {
          VT[(size_t)(col - DMODEL - HDIM) * S_LEN + row] = (f16)v;
        } else {
          C[(size_t)row * N + col] = (OutT)v;
        }
      }
    }
  }
}

// ---------------- Split-KV flash MQA attention ----------------------------
// grid (qt=32, ch=4, head=16), block = 2 waves x 32 q-rows. Each block does
// KV chunk [ch*512, min((qt+1)*64, ch*512+512)). qt<8 => single chunk,
// writes ctx directly; else writes unnormalized partials (O f16, m/l f32).
__global__ __launch_bounds__(128) void flash_mqa_split(
    const f16* __restrict__ qkv, const f16* __restrict__ vt, f16* __restrict__ ctx,
    f16* __restrict__ Opart, float* __restrict__ mlbuf) {
  const int qt = blockIdx.x;
  const int ch = blockIdx.y;
  const int head = blockIdx.z;
  if (ch * 8 > qt) return;  // chunk beyond causal range (uniform per block)

  __shared__ __align__(16) f16 Plds[2][32][72];
  const int tid = threadIdx.x;
  const int wv = tid >> 6;
  const int l = tid & 63;
  const int lg = l >> 4, lm = l & 15;
  const int wq0 = qt * 64 + wv * 32;
  const float alpha = 0.08838834764831845f * 1.4426950408889634f;  // scale*log2e

  // Q fragments in registers for the whole chunk.
  f16x8 qf[2][4];
#pragma unroll
  for (int mf = 0; mf < 2; ++mf)
#pragma unroll
    for (int ks = 0; ks < 4; ++ks)
      qf[mf][ks] = *reinterpret_cast<const f16x8*>(
          qkv + (size_t)(wq0 + mf * 16 + lm) * EQKV + head * HDIM + ks * 32 + lg * 8);

  f32x4 o[2][8] = {};
  float m_row[2][4], l_row[2][4];
#pragma unroll
  for (int mf = 0; mf < 2; ++mf)
#pragma unroll
    for (int j = 0; j < 4; ++j) {
      m_row[mf][j] = -__builtin_inff();
      l_row[mf][j] = 0.f;
    }

  const int kt0 = ch * 8;
  const int kt1 = min(qt + 1, kt0 + 8);
  for (int t = kt0; t < kt1; ++t) {
    const int k0 = t * 64;
    // ---- scores S[32][64] = Q * K^T ----
    f32x4 sc[2][4] = {};
#pragma unroll
    for (int ks = 0; ks < 4; ++ks) {
#pragma unroll
      for (int nf = 0; nf < 4; ++nf) {
        f16x8 kf = *reinterpret_cast<const f16x8*>(
            qkv + (size_t)(k0 + nf * 16 + lm) * EQKV + DMODEL + ks * 32 + lg * 8);
        sc[0][nf] = MFMA16(qf[0][ks], kf, sc[0][nf]);
        sc[1][nf] = MFMA16(qf[1][ks], kf, sc[1][nf]);
      }
    }
    // ---- causal mask on diagonal tile ----
    if (t == qt) {
#pragma unroll
      for (int mf = 0; mf < 2; ++mf)
#pragma unroll
        for (int nf = 0; nf < 4; ++nf)
#pragma unroll
          for (int j = 0; j < 4; ++j) {
            int row = wq0 + mf * 16 + lg * 4 + j;
            int col = k0 + nf * 16 + lm;
            if (col > row) sc[mf][nf][j] = -__builtin_inff();
          }
    }
    // ---- online softmax ----
#pragma unroll
    for (int mf = 0; mf < 2; ++mf) {
      float tm[4], rj[4], rs[4];
#pragma unroll
      for (int j = 0; j < 4; ++j)
        tm[j] = fmaxf(fmaxf(sc[mf][0][j], sc[mf][1][j]), fmaxf(sc[mf][2][j], sc[mf][3][j]));
#pragma unroll
      for (int j = 0; j < 4; ++j) {
#pragma unroll
        for (int d = 1; d < 16; d <<= 1) tm[j] = fmaxf(tm[j], __shfl_xor(tm[j], d));
      }
#pragma unroll
      for (int j = 0; j < 4; ++j) {
        float mn = fmaxf(m_row[mf][j], tm[j] * alpha);
        rj[j] = exp2f(m_row[mf][j] - mn);
        m_row[mf][j] = mn;
        l_row[mf][j] *= rj[j];
        rs[j] = 0.f;
      }
#pragma unroll
      for (int nf = 0; nf < 4; ++nf)
#pragma unroll
        for (int j = 0; j < 4; ++j) {
          float p = exp2f(sc[mf][nf][j] * alpha - m_row[mf][j]);
          rs[j] += p;
          Plds[wv][mf * 16 + lg * 4 + j][nf * 16 + lm] = (f16)p;
        }
#pragma unroll
      for (int j = 0; j < 4; ++j) {
#pragma unroll
        for (int d = 1; d < 16; d <<= 1) rs[j] += __shfl_xor(rs[j], d);
        l_row[mf][j] += rs[j];
      }
#pragma unroll
      for (int df = 0; df < 8; ++df)
#pragma unroll
        for (int j = 0; j < 4; ++j) o[mf][df][j] *= rj[j];
    }
    asm volatile("s_waitcnt lgkmcnt(0)" ::: "memory");
    __builtin_amdgcn_sched_barrier(0);
    // ---- PV: O += P[32][64] * V[64][128] ----
#pragma unroll
    for (int kk = 0; kk < 2; ++kk) {
      f16x8 pa[2];
#pragma unroll
      for (int mf = 0; mf < 2; ++mf)
        pa[mf] = *reinterpret_cast<const f16x8*>(&Plds[wv][mf * 16 + lm][kk * 32 + lg * 8]);
#pragma unroll
      for (int df = 0; df < 8; ++df) {
        f16x8 vf = *reinterpret_cast<const f16x8*>(
            vt + (size_t)(df * 16 + lm) * S_LEN + k0 + kk * 32 + lg * 8);
        o[0][df] = MFMA16(pa[0], vf, o[0][df]);
        o[1][df] = MFMA16(pa[1], vf, o[1][df]);
      }
    }
  }

  if (qt < 8) {
    // single chunk: normalized direct write
#pragma unroll
    for (int mf = 0; mf < 2; ++mf)
#pragma unroll
      for (int j = 0; j < 4; ++j) {
        float inv = 1.0f / l_row[mf][j];
        int row = wq0 + mf * 16 + lg * 4 + j;
#pragma unroll
        for (int df = 0; df < 8; ++df)
          ctx[(size_t)row * DMODEL + head * HDIM + df * 16 + lm] =
              (f16)(o[mf][df][j] * inv);
      }
  } else {
    const int slot = (head * 32 + qt) * 4 + ch;
    f16* Op = Opart + (size_t)slot * (64 * 128);
    float* mlp = mlbuf + (size_t)slot * 128;
#pragma unroll
    for (int mf = 0; mf < 2; ++mf)
#pragma unroll
      for (int j = 0; j < 4; ++j) {
        int rl = wv * 32 + mf * 16 + lg * 4 + j;
#pragma unroll
        for (int df = 0; df < 8; ++df)
          Op[rl * 128 + df * 16 + lm] = (f16)o[mf][df][j];
        if (lm == 0) {
          mlp[rl * 2] = m_row[mf][j];
          mlp[rl * 2 + 1] = l_row[mf][j];
        }
      }
  }
}

// ---------------- combine partial chunks ----------------------------------
// grid (qt=32, head=16), 256 thr: thread = (row 0..63, col-group 0..3 of 32).
__global__ __launch_bounds__(256) void flash_combine(
    const f16* __restrict__ Opart, const float* __restrict__ mlbuf,
    f16* __restrict__ ctx) {
  const int qt = blockIdx.x, head = blockIdx.y;
  if (qt < 8) return;  // direct-written by split kernel
  const int nch = (qt >> 3) + 1;  // 2..4
  const int tid = threadIdx.x;
  const int row = tid >> 2, cg = tid & 3;
  const int slot0 = (head * 32 + qt) * 4;

  float m[4], lv[4], w[4];
  float mmax = -__builtin_inff();
#pragma unroll
  for (int i = 0; i < 4; ++i) {
    if (i < nch) {
      m[i] = mlbuf[(size_t)(slot0 + i) * 128 + row * 2];
      lv[i] = mlbuf[(size_t)(slot0 + i) * 128 + row * 2 + 1];
    } else {
      m[i] = -__builtin_inff();
      lv[i] = 0.f;
    }
    mmax = fmaxf(mmax, m[i]);
  }
  float L = 0.f;
#pragma unroll
  for (int i = 0; i < 4; ++i) {
    w[i] = (i < nch) ? exp2f(m[i] - mmax) : 0.f;
    L += w[i] * lv[i];
  }
  const float invL = 1.0f / L;
  const int rowg = qt * 64 + row;

#pragma unroll
  for (int g = 0; g < 4; ++g) {
    float acc[8] = {0.f, 0.f, 0.f, 0.f, 0.f, 0.f, 0.f, 0.f};
#pragma unroll
    for (int i = 0; i < 4; ++i) {
      if (i < nch) {
        f16x8 v = *reinterpret_cast<const f16x8*>(
            Opart + (size_t)(slot0 + i) * 8192 + row * 128 + cg * 32 + g * 8);
#pragma unroll
        for (int j = 0; j < 8; ++j) acc[j] += w[i] * (float)v[j];
      }
    }
    f16x8 ov;
#pragma unroll
    for (int j = 0; j < 8; ++j) ov[j] = (f16)(acc[j] * invL);
    *reinterpret_cast<f16x8*>(ctx + (size_t)rowg * DMODEL + head * HDIM + cg * 32 + g * 8) = ov;
  }
}

// ---------------- legacy single-pass flash (ws fallback) ------------------
__global__ __launch_bounds__(128) void flash_mqa(
    const f16* __restrict__ qkv, const f16* __restrict__ vt, f16* __restrict__ ctx) {
  __shared__ __align__(16) f16 Plds[2][32][72];
  const int tid = threadIdx.x;
  const int wv = tid >> 6;
  const int l = tid & 63;
  const int lg = l >> 4, lm = l & 15;
  const int head = blockIdx.y;
  const int qt = blockIdx.x;
  const int wq0 = qt * 64 + wv * 32;
  const float alpha = 0.08838834764831845f * 1.4426950408889634f;

  f16x8 qf[2][4];
#pragma unroll
  for (int mf = 0; mf < 2; ++mf)
#pragma unroll
    for (int ks = 0; ks < 4; ++ks)
      qf[mf][ks] = *reinterpret_cast<const f16x8*>(
          qkv + (size_t)(wq0 + mf * 16 + lm) * EQKV + head * HDIM + ks * 32 + lg * 8);

  f32x4 o[2][8] = {};
  float m_row[2][4], l_row[2][4];
#pragma unroll
  for (int mf = 0; mf < 2; ++mf)
#pragma unroll
    for (int j = 0; j < 4; ++j) {
      m_row[mf][j] = -__builtin_inff();
      l_row[mf][j] = 0.f;
    }

  const int nt = qt + 1;
  for (int t = 0; t < nt; ++t) {
    const int k0 = t * 64;
    f32x4 sc[2][4] = {};
#pragma unroll
    for (int ks = 0; ks < 4; ++ks) {
#pragma unroll
      for (int nf = 0; nf < 4; ++nf) {
        f16x8 kf = *reinterpret_cast<const f16x8*>(
            qkv + (size_t)(k0 + nf * 16 + lm) * EQKV + DMODEL + ks * 32 + lg * 8);
        sc[0][nf] = MFMA16(qf[0][ks], kf, sc[0][nf]);
        sc[1][nf] = MFMA16(qf[1][ks], kf, sc[1][nf]);
      }
    }
    if (t == nt - 1) {
#pragma unroll
      for (int mf = 0; mf < 2; ++mf)
#pragma unroll
        for (int nf = 0; nf < 4; ++nf)
#pragma unroll
          for (int j = 0; j < 4; ++j) {
            int row = wq0 + mf * 16 + lg * 4 + j;
            int col = k0 + nf * 16 + lm;
            if (col > row) sc[mf][nf][j] = -__builtin_inff();
          }
    }
#pragma unroll
    for (int mf = 0; mf < 2; ++mf) {
      float tm[4], rj[4], rs[4];
#pragma unroll
      for (int j = 0; j < 4; ++j)
        tm[j] = fmaxf(fmaxf(sc[mf][0][j], sc[mf][1][j]), fmaxf(sc[mf][2][j], sc[mf][3][j]));
#pragma unroll
      for (int j = 0; j < 4; ++j) {
#pragma unroll
        for (int d = 1; d < 16; d <<= 1) tm[j] = fmaxf(tm[j], __shfl_xor(tm[j], d));
      }
#pragma unroll
      for (int j = 0; j < 4; ++j) {
        float mn = fmaxf(m_row[mf][j], tm[j] * alpha);
        rj[j] = exp2f(m_row[mf][j] - mn);
        m_row[mf][j] = mn;
        l_row[mf][j] *= rj[j];
        rs[j] = 0.f;
      }
#pragma unroll
      for (int nf = 0; nf < 4; ++nf)
#pragma unroll
        for (int j = 0; j < 4; ++j) {
          float p = exp2f(sc[mf][nf][j] * alpha - m_row[mf][j]);
          rs[j] += p;
          Plds[wv][mf * 16 + lg * 4 + j][nf * 16 + lm] = (f16)p;
        }
#pragma unroll
      for (int j = 0; j < 4; ++j) {
#pragma unroll
        for (int d = 1; d < 16; d <<= 1) rs[j] += __shfl_xor(rs[j], d);
        l_row[mf][j] += rs[j];
      }
#pragma unroll
      for (int df = 0; df < 8; ++df)
#pragma unroll
        for (int j = 0; j < 4; ++j) o[mf][df][j] *= rj[j];
    }
    asm volatile("s_waitcnt lgkmcnt(0)" ::: "memory");
    __builtin_amdgcn_sched_barrier(0);
#pragma unroll
    for (int kk = 0; kk < 2; ++kk) {
      f16x8 pa[2];
#pragma unroll
      for (int mf = 0; mf < 2; ++mf)
        pa[mf] = *reinterpret_cast<const f16x8*>(&Plds[wv][mf * 16 + lm][kk * 32 + lg * 8]);
#pragma unroll
      for (int df = 0; df < 8; ++df) {
        f16x8 vf = *reinterpret_cast<const f16x8*>(
            vt + (size_t)(df * 16 + lm) * S_LEN + k0 + kk * 32 + lg * 8);
        o[0][df] = MFMA16(pa[0], vf, o[0][df]);
        o[1][df] = MFMA16(pa[1], vf, o[1][df]);
      }
    }
  }
#pragma unroll
  for (int mf = 0; mf < 2; ++mf)
#pragma unroll
    for (int j = 0; j < 4; ++j) {
      float inv = 1.0f / l_row[mf][j];
      int row = wq0 + mf * 16 + lg * 4 + j;
#pragma unroll
      for (int df = 0; df < 8; ++df)
        ctx[(size_t)row * DMODEL + head * HDIM + df * 16 + lm] =
            (f16)(o[mf][df][j] * inv);
    }
}

// ---------------- host launcher -------------------------------------------
extern "C" void kernel_launch(void* const* d_in, const int* in_sizes, int n_in,
                              void* d_out, int out_size, void* d_ws, size_t ws_size,
                              hipStream_t stream) {
  const float* x = (const float*)d_in[0];
  const float* Wqkv_w = (const float*)d_in[1];
  const float* Wqkv_b = (const float*)d_in[2];
  const float* out_w = (const float*)d_in[3];
  const float* out_b = (const float*)d_in[4];

  char* p = (char*)d_ws;
  f16* xh = (f16*)p;    p += (size_t)S_LEN * DMODEL * 2;
  f16* wqh = (f16*)p;   p += (size_t)EQKV * DMODEL * 2;
  f16* owh = (f16*)p;   p += (size_t)DMODEL * DMODEL * 2;
  f16* qkvh = (f16*)p;  p += (size_t)S_LEN * EQKV * 2;
  f16* vth = (f16*)p;   p += (size_t)HDIM * S_LEN * 2;
  f16* ctxh = (f16*)p;  p += (size_t)S_LEN * DMODEL * 2;
  // split-KV partials: 2048 slots (16 heads x 32 qt x 4 chunks)
  f16* Opart = (f16*)p;   p += (size_t)2048 * 64 * 128 * 2;  // 33.5 MB
  float* mlbuf = (float*)p; p += (size_t)2048 * 128 * 4;     // 1 MB
  const size_t need = (size_t)(p - (char*)d_ws);
  const bool use_split = ws_size >= need;

  f32_to_f16_kernel<<<(S_LEN * DMODEL / 4) / 256, 256, 0, stream>>>(x, xh, S_LEN * DMODEL / 4);
  f32_to_f16_kernel<<<(EQKV * DMODEL / 4) / 256, 256, 0, stream>>>(Wqkv_w, wqh, EQKV * DMODEL / 4);
  f32_to_f16_kernel<<<(DMODEL * DMODEL / 4) / 256, 256, 0, stream>>>(out_w, owh, DMODEL * DMODEL / 4);

  gemm_bt<f16, true><<<dim3(S_LEN / 64, EQKV / 128), 256, 0, stream>>>(
      xh, wqh, Wqkv_b, qkvh, vth, S_LEN, EQKV, DMODEL);

  if (use_split) {
    flash_mqa_split<<<dim3(32, 4, 16), 128, 0, stream>>>(qkvh, vth, ctxh, Opart, mlbuf);
    flash_combine<<<dim3(32, 16), 256, 0, stream>>>(Opart, mlbuf, ctxh);
  } else {
    flash_mqa<<<dim3(32, 16), 128, 0, stream>>>(qkvh, vth, ctxh);
  }

  gemm_bt<float, false><<<dim3(S_LEN / 64, DMODEL / 128), 256, 0, stream>>>(
      ctxh, owh, out_b, (float*)d_out, nullptr, S_LEN, DMODEL, DMODEL);
}